// Round 1
// baseline (75.372 us; speedup 1.0000x reference)
//
#include <hip/hip_runtime.h>
#include <stdint.h>
#include <math.h>

#define THREADS 1024
#define NBINS 8192
#define BIN_SHIFT 19
#define CAND_MAX 2048
#define MAXK 64

// order-preserving fp32 -> uint32 key
__device__ __forceinline__ uint32_t fkey(float f) {
    uint32_t b = __float_as_uint(f);
    return (b & 0x80000000u) ? ~b : (b | 0x80000000u);
}
__device__ __forceinline__ float fval(uint32_t k) {
    uint32_t b = (k & 0x80000000u) ? (k & 0x7FFFFFFFu) : ~k;
    return __uint_as_float(b);
}

__global__ __launch_bounds__(THREADS) void sampler_kernel(
    const float* __restrict__ logits,
    const float* __restrict__ temperature,
    const float* __restrict__ top_p,
    const int* __restrict__ token_lengths,
    const int* __restrict__ top_k_ptr,
    int* __restrict__ out, int V)
{
    const int row = blockIdx.x;
    const int tid = threadIdx.x;
    int K = *top_k_ptr;
    if (K < 1) K = 1;
    if (K > MAXK) K = MAXK;

    __shared__ uint32_t s_hist[NBINS];
    __shared__ uint32_t s_chunk[THREADS];
    __shared__ unsigned long long s_cand[CAND_MAX];
    __shared__ unsigned long long s_top[MAXK];
    __shared__ float s_vals[MAXK];
    __shared__ int s_idx[MAXK];
    __shared__ int s_slot[MAXK];
    __shared__ int s_T, s_cnt;

    // ---------- phase 1: histogram over ordered-key top 13 bits ----------
    for (int i = tid; i < NBINS; i += THREADS) s_hist[i] = 0u;
    if (tid == 0) s_cnt = 0;
    __syncthreads();

    const float* rowbase = logits + (size_t)row * (size_t)V;
    const bool vec_ok = ((V & 3) == 0);
    const int nv = V >> 2;

    if (vec_ok) {
        const float4* rowp = reinterpret_cast<const float4*>(rowbase);
        for (int j = tid; j < nv; j += THREADS) {
            float4 x = rowp[j];
            atomicAdd(&s_hist[fkey(x.x) >> BIN_SHIFT], 1u);
            atomicAdd(&s_hist[fkey(x.y) >> BIN_SHIFT], 1u);
            atomicAdd(&s_hist[fkey(x.z) >> BIN_SHIFT], 1u);
            atomicAdd(&s_hist[fkey(x.w) >> BIN_SHIFT], 1u);
        }
    } else {
        for (int j = tid; j < V; j += THREADS)
            atomicAdd(&s_hist[fkey(rowbase[j]) >> BIN_SHIFT], 1u);
    }
    __syncthreads();

    // ---------- phase 2: threshold bin T (count of bins >= T is >= K) ----------
    const int CHUNK = NBINS / THREADS;  // 8
    {
        uint32_t cs = 0;
        const int base = tid * CHUNK;
        #pragma unroll
        for (int b = 0; b < CHUNK; ++b) cs += s_hist[base + b];
        s_chunk[tid] = cs;
    }
    __syncthreads();
    // parallel suffix-sum (Hillis-Steele from the right) over 1024 chunk sums
    for (int off = 1; off < THREADS; off <<= 1) {
        uint32_t v = (tid + off < THREADS) ? s_chunk[tid + off] : 0u;
        __syncthreads();
        s_chunk[tid] += v;
        __syncthreads();
    }
    {
        uint32_t suf  = s_chunk[tid];
        uint32_t sufn = (tid + 1 < THREADS) ? s_chunk[tid + 1] : 0u;
        if (suf >= (uint32_t)K && sufn < (uint32_t)K) {
            // my chunk contains the K-th-from-top boundary
            uint32_t acc = sufn;
            int T = tid * CHUNK;
            for (int b = tid * CHUNK + CHUNK - 1; b >= tid * CHUNK; --b) {
                acc += s_hist[b];
                if (acc >= (uint32_t)K) { T = b; break; }
            }
            s_T = T;
        }
    }
    __syncthreads();

    // ---------- phase 3: collect candidates with bin >= T ----------
    const uint32_t T = (uint32_t)s_T;
    if (vec_ok) {
        const float4* rowp = reinterpret_cast<const float4*>(rowbase);
        for (int j = tid; j < nv; j += THREADS) {
            float4 x = rowp[j];
            const uint32_t base = (uint32_t)(j << 2);
            uint32_t k;
            k = fkey(x.x); if ((k >> BIN_SHIFT) >= T) { int p = atomicAdd(&s_cnt, 1); if (p < CAND_MAX) s_cand[p] = ((unsigned long long)k << 32) | (uint32_t)~(base + 0u); }
            k = fkey(x.y); if ((k >> BIN_SHIFT) >= T) { int p = atomicAdd(&s_cnt, 1); if (p < CAND_MAX) s_cand[p] = ((unsigned long long)k << 32) | (uint32_t)~(base + 1u); }
            k = fkey(x.z); if ((k >> BIN_SHIFT) >= T) { int p = atomicAdd(&s_cnt, 1); if (p < CAND_MAX) s_cand[p] = ((unsigned long long)k << 32) | (uint32_t)~(base + 2u); }
            k = fkey(x.w); if ((k >> BIN_SHIFT) >= T) { int p = atomicAdd(&s_cnt, 1); if (p < CAND_MAX) s_cand[p] = ((unsigned long long)k << 32) | (uint32_t)~(base + 3u); }
        }
    } else {
        for (int j = tid; j < V; j += THREADS) {
            uint32_t k = fkey(rowbase[j]);
            if ((k >> BIN_SHIFT) >= T) { int p = atomicAdd(&s_cnt, 1); if (p < CAND_MAX) s_cand[p] = ((unsigned long long)k << 32) | (uint32_t)~(uint32_t)j; }
        }
    }
    __syncthreads();

    // ---------- phase 4+: single wave does selection + sampler math ----------
    if (tid >= 64) return;          // no __syncthreads below this point
    const int M = min(s_cnt, CAND_MAX);

    // top-K selection: K rounds of wave max-reduce (value desc, index asc tie-break)
    for (int t = 0; t < K; ++t) {
        unsigned long long best = 0ull;
        for (int j = tid; j < M; j += 64) { unsigned long long u = s_cand[j]; if (u > best) best = u; }
        #pragma unroll
        for (int off = 1; off < 64; off <<= 1) {
            uint32_t lo = (uint32_t)best, hi = (uint32_t)(best >> 32);
            lo = (uint32_t)__shfl_xor((int)lo, off, 64);
            hi = (uint32_t)__shfl_xor((int)hi, off, 64);
            unsigned long long o = ((unsigned long long)hi << 32) | lo;
            if (o > best) best = o;
        }
        for (int j = tid; j < M; j += 64) if (s_cand[j] == best) s_cand[j] = 0ull;
        if (tid == 0) s_top[t] = best;
        __builtin_amdgcn_wave_barrier();
    }

    if (tid < K) {
        unsigned long long u = s_top[tid];
        s_idx[tid]  = (int)(~(uint32_t)u);
        s_vals[tid] = fval((uint32_t)(u >> 32));
    }
    __builtin_amdgcn_wave_barrier();

    const float temp = temperature[row];
    const float tp   = top_p[row];

    // ----- stage 1 softmax over K scaled values (lane i owns slot i) -----
    const float a0 = s_vals[0] / temp;
    float e = 0.f;
    int myidx = -1;
    if (tid < K) {
        myidx = s_idx[tid];
        e = expf(s_vals[tid] / temp - a0);
    }
    float sum = e;
    #pragma unroll
    for (int off = 1; off < 64; off <<= 1) sum += __shfl_xor(sum, off, 64);
    const float p1 = e / sum;

    // suffix-inclusive cumsum (ascending-order cumsum of reference): cs_i = sum_{j>=i} p1_j
    float cs = p1;
    #pragma unroll
    for (int off = 1; off < 64; off <<= 1) {
        float o = __shfl_down(cs, off, 64);
        cs += (tid + off < 64) ? o : 0.f;
    }
    // reference masks slot iff csum <= (1-top_p); slot 0 force-kept
    const float lim = 1.0f - tp;
    const bool keep = (tid < K) && (tid == 0 || cs > lim);
    const int S = __popcll(__ballot(keep));   // survivors are the descending prefix [0,S)

    // ----- stage 2 re-softmax over survivors -----
    float e2 = (tid < S) ? e : 0.f;
    float sum2 = e2;
    #pragma unroll
    for (int off = 1; off < 64; off <<= 1) sum2 += __shfl_xor(sum2, off, 64);
    const float p2 = e2 / sum2;

    // EOS rule
    const bool is_eos = (tid < S) && (myidx == 2);
    float eosp = is_eos ? p2 : 0.f;
    #pragma unroll
    for (int off = 1; off < 64; off <<= 1) eosp += __shfl_xor(eosp, off, 64);
    const bool has_eos = (__ballot(is_eos) != 0ull);
    const float eth = fmaxf(eosp / 100.0f, 0.005f);

    // ----- slot indices: survivors keep their token idx; padding = smallest absent ints -----
    if (tid < S) s_slot[tid] = myidx;
    __builtin_amdgcn_wave_barrier();
    if (tid == 0) {
        unsigned long long m0 = 0ull, m1 = 0ull;
        for (int i = 0; i < S; ++i) {
            int id = s_idx[i];
            if (id < 64) m0 |= 1ull << id;
            else if (id < 128) m1 |= 1ull << (id - 64);
        }
        int nxt = 0;
        for (int i = S; i < K; ++i) {
            while ((nxt < 64) ? ((m0 >> nxt) & 1ull) : ((m1 >> (nxt - 64)) & 1ull)) nxt++;
            s_slot[i] = nxt++;
        }
    }
    __builtin_amdgcn_wave_barrier();

    // ----- length softmax over all K slots -----
    float len = -INFINITY;
    if (tid < K) {
        int id = s_slot[tid];
        id = (id < 0) ? 0 : ((id >= V) ? V - 1 : id);
        len = (float)token_lengths[id];
    }
    float lmax = len;
    #pragma unroll
    for (int off = 1; off < 64; off <<= 1) lmax = fmaxf(lmax, __shfl_xor(lmax, off, 64));
    float el = (tid < K) ? expf(len - lmax) : 0.f;
    float lsum = el;
    #pragma unroll
    for (int off = 1; off < 64; off <<= 1) lsum += __shfl_xor(lsum, off, 64);
    const float ls = el / lsum;

    // ----- mix + masks + first-occurrence argmax -----
    float mix = -INFINITY;
    if (tid < S) {
        mix = 0.5f * p2 + 0.5f * ls;
        if (!(p2 >= 0.001f)) mix = -INFINITY;
        if (has_eos && !(p2 >= eth)) mix = -INFINITY;
    }
    float bm = mix; int bi = tid;
    #pragma unroll
    for (int off = 1; off < 64; off <<= 1) {
        float om = __shfl_xor(bm, off, 64);
        int   oi = __shfl_xor(bi, off, 64);
        if (om > bm || (om == bm && oi < bi)) { bm = om; bi = oi; }
    }

    if (tid == 0) {
        int chosen = s_slot[bi];          // padding can't win (mix=-inf; slot0 always finite)
        if (temp < 1e-5f) chosen = s_idx[0];   // greedy branch (never taken for this data)
        out[row] = chosen;
    }
}

extern "C" void kernel_launch(void* const* d_in, const int* in_sizes, int n_in,
                              void* d_out, int out_size, void* d_ws, size_t ws_size,
                              hipStream_t stream) {
    const float* logits        = (const float*)d_in[0];
    const float* temperature   = (const float*)d_in[1];
    const float* top_p         = (const float*)d_in[2];
    const int*   token_lengths = (const int*)d_in[3];
    const int*   top_k_ptr     = (const int*)d_in[4];
    int* outp = (int*)d_out;

    const int B = in_sizes[1];   // temperature length
    const int V = in_sizes[3];   // token_lengths length

    sampler_kernel<<<B, THREADS, 0, stream>>>(logits, temperature, top_p,
                                              token_lengths, top_k_ptr, outp, V);
}